// Round 8
// baseline (88.088 us; speedup 1.0000x reference)
//
#include <hip/hip_runtime.h>
#include <math.h>

#define EPSF 1e-5f

// problem sizes
#define BB 2
#define NN 6
#define KPIX 1680      // 28*60
#define QQ 1024        // 32*32
#define SPLIT 6
#define KCHUNK (KPIX/SPLIT)   // 280
#define NPART (NN*SPLIT)      // 36
#define QKSCALE (0.17677669529663687f * 1.4426950408889634f)  // 32^-0.5 * log2(e)
#define NTILE_KV 53    // ceil(1680/32)

// prepacked weight offsets (bf16 elements)
#define WOFF_FP   0
#define WOFF_FL   16384
#define WOFF_K    32768
#define WOFF_V    49152
#define WOFF_Q    65536
#define WOFF_PROJ 81920
#define WOFF_W1   98304
#define WOFF_W2   131072
#define WPK_ELEMS 163840

typedef __attribute__((ext_vector_type(8))) short bf16x8;
typedef __attribute__((ext_vector_type(16))) float f32x16;

__device__ __forceinline__ unsigned short f2bf(float f) {
  union { float f; unsigned u; } v; v.f = f;
  unsigned r = v.u + 0x7FFFu + ((v.u >> 16) & 1u);   // RNE
  return (unsigned short)(r >> 16);
}
__device__ __forceinline__ float bf2f(unsigned short u) {
  union { unsigned u; float f; } v; v.u = ((unsigned)u) << 16; return v.f;
}
__device__ __forceinline__ unsigned pk_bf16(float lo, float hi) {
  unsigned r;
  asm volatile("v_cvt_pk_bf16_f32 %0, %1, %2" : "=v"(r) : "v"(lo), "v"(hi));
  return r;
}
__device__ __forceinline__ float fast_exp2(float x) {
  return __builtin_amdgcn_exp2f(x);   // native v_exp_f32 (base-2)
}
// half_swap: exchange 32-lane halves between a and b
__device__ __forceinline__ void half_swap(unsigned &a, unsigned &b) {
#if __has_builtin(__builtin_amdgcn_permlane32_swap)
  auto r = __builtin_amdgcn_permlane32_swap(a, b, false, false);
  a = (unsigned)r[0]; b = (unsigned)r[1];
#else
  unsigned sa = (unsigned)__shfl_xor((int)a, 32);
  unsigned sb = (unsigned)__shfl_xor((int)b, 32);
  int hi = (threadIdx.x & 63) >> 5;
  unsigned na = hi ? sb : a;
  unsigned nb = hi ? b : sa;
  a = na; b = nb;
#endif
}

// --- weight prepack to bf16 fragment-friendly layouts
__global__ void prepack_kernel(const float* __restrict__ fp_w, const float* __restrict__ fl_w,
                               const float* __restrict__ k_w, const float* __restrict__ v_w,
                               const float* __restrict__ q_w, const float* __restrict__ proj_w,
                               const float* __restrict__ mlp_w1, const float* __restrict__ mlp_w2,
                               unsigned short* __restrict__ wp) {
  int blk = blockIdx.x;
  int c = threadIdx.x;
  if (blk < 640) {
    int mat = blk >> 7, o = blk & 127;
    float v;
    if (mat == 0)      v = fp_w[o*128 + c];
    else if (mat == 1) v = fl_w[o*128 + c];
    else if (mat == 2) v = k_w[c*128 + o];
    else if (mat == 3) v = v_w[c*128 + o];
    else               v = q_w[c*128 + o] * QKSCALE;
    wp[(size_t)mat*16384 + o*128 + c] = f2bf(v);
  } else if (blk < 768) {
    int row = blk - 640;                         // proj^T [o][i]
    wp[WOFF_PROJ + row*128 + c] = f2bf(proj_w[c*128 + row]);
  } else if (blk < 1024) {
    int row = blk - 768;                         // w1^T [h][i]
    wp[WOFF_W1 + row*128 + c] = f2bf(mlp_w1[c*256 + row]);
  } else {
    int i2 = blk - 1024;                         // w2^T [o][h]
    int row = i2 >> 1, col = (i2 & 1)*128 + c;
    wp[WOFF_W2 + row*256 + col] = f2bf(mlp_w2[col*128 + row]);
  }
}

// --- camera-center embedding
__global__ void ce_kernel(const float* __restrict__ cam_w, const float* __restrict__ E_inv,
                          float* __restrict__ c_embed) {
  int bn = blockIdx.x; int t = threadIdx.x;
  const float* E = E_inv + bn * 16;
  float s = cam_w[t*4+0]*E[3] + cam_w[t*4+1]*E[7] + cam_w[t*4+2]*E[11] + cam_w[t*4+3]*E[15];
  c_embed[bn*128 + t] = s;
}

// --- MFMA kv (round-4/5 replay-stable 4-wave version)
__global__ __launch_bounds__(256) void kv_kernel(
    const float* __restrict__ feature, const float* __restrict__ I_inv,
    const float* __restrict__ E_inv, const float* __restrict__ image_plane,
    const float* __restrict__ c_embed, const float* __restrict__ img_w,
    const float* __restrict__ fp_bn_g, const float* __restrict__ fp_bn_b,
    const float* __restrict__ fp_bn_m, const float* __restrict__ fp_bn_v,
    const float* __restrict__ fl_bn_g, const float* __restrict__ fl_bn_b,
    const float* __restrict__ fl_bn_m, const float* __restrict__ fl_bn_v,
    const float* __restrict__ k_ln_g, const float* __restrict__ k_ln_b,
    const float* __restrict__ k_b,
    const float* __restrict__ v_ln_g, const float* __restrict__ v_ln_b,
    const float* __restrict__ v_b,
    const unsigned short* __restrict__ wp,
    unsigned short* __restrict__ khb, unsigned short* __restrict__ vtb)
{
  int blk = blockIdx.x;
  int bn = blk / NTILE_KV, tp = blk % NTILE_KV;
  int p0 = tp * 32;
  int t = threadIdx.x;
  int wv = t >> 6, l = t & 63, lo = l & 31, hi = l >> 5;

  __shared__ unsigned short sA[2][32*128];
  __shared__ float sD[4][32];
  __shared__ float sRed[5][4][32];

  if (t < 32) {
    int pix = min(p0 + t, KPIX-1);
    const float* Ii = I_inv + bn*9;
    const float* Ei = E_inv + bn*16;
    float px = image_plane[pix], py = image_plane[KPIX + pix], pz = image_plane[2*KPIX + pix];
    float c0 = Ii[0]*px + Ii[1]*py + Ii[2]*pz;
    float c1 = Ii[3]*px + Ii[4]*py + Ii[5]*pz;
    float c2 = Ii[6]*px + Ii[7]*py + Ii[8]*pz;
    sD[0][t] = Ei[0]*c0 + Ei[1]*c1 + Ei[2]*c2  + Ei[3];
    sD[1][t] = Ei[4]*c0 + Ei[5]*c1 + Ei[6]*c2  + Ei[7];
    sD[2][t] = Ei[8]*c0 + Ei[9]*c1 + Ei[10]*c2 + Ei[11];
    sD[3][t] = Ei[12]*c0 + Ei[13]*c1 + Ei[14]*c2 + Ei[15];
  }

  {
    int c = t >> 1, ph = t & 1;
    float gp = fp_bn_g[c]*rsqrtf(fp_bn_v[c]+EPSF); float bp = fp_bn_b[c] - fp_bn_m[c]*gp;
    float gl = fl_bn_g[c]*rsqrtf(fl_bn_v[c]+EPSF); float bl = fl_bn_b[c] - fl_bn_m[c]*gl;
    const float* frow = feature + ((size_t)bn*128 + c)*KPIX;
#pragma unroll
    for (int i = 0; i < 4; ++i) {
      int plb = ph*16 + 4*i;
      int pix = p0 + plb;
      float4 f;
      if (pix + 3 < KPIX) f = *(const float4*)(frow + pix);
      else {
        f.x = frow[min(pix+0, KPIX-1)]; f.y = frow[min(pix+1, KPIX-1)];
        f.z = frow[min(pix+2, KPIX-1)]; f.w = frow[min(pix+3, KPIX-1)];
      }
      float fv[4] = {f.x, f.y, f.z, f.w};
#pragma unroll
      for (int j = 0; j < 4; ++j) {
        int pl = plb + j;
        int cc = c ^ ((pl & 7) << 3);
        sA[0][pl*128 + cc] = f2bf(fmaxf(fv[j]*gp + bp, 0.f));
        sA[1][pl*128 + cc] = f2bf(fmaxf(fv[j]*gl + bl, 0.f));
      }
    }
  }
  __syncthreads();

  f32x16 acck = {}, accv = {};
  {
    const unsigned short* wfp = wp + WOFF_FP + (32*wv + lo)*128 + hi*8;
    const unsigned short* wfl = wp + WOFF_FL + (32*wv + lo)*128 + hi*8;
    int swz = (lo & 7) << 3;
#pragma unroll
    for (int s = 0; s < 8; ++s) {
      int cbase = s*16 + hi*8;
      bf16x8 a0 = *(const bf16x8*)(wfp + s*16);
      bf16x8 a1 = *(const bf16x8*)(wfl + s*16);
      bf16x8 b0 = *(const bf16x8*)&sA[0][lo*128 + (cbase ^ swz)];
      bf16x8 b1 = *(const bf16x8*)&sA[1][lo*128 + (cbase ^ swz)];
      acck = __builtin_amdgcn_mfma_f32_32x32x16_bf16(a0, b0, acck, 0, 0, 0);
      accv = __builtin_amdgcn_mfma_f32_32x32x16_bf16(a1, b1, accv, 0, 0, 0);
    }
  }

  float d0 = sD[0][lo], d1 = sD[1][lo], d2 = sD[2][lo], d3 = sD[3][lo];

  float ime[16];
  float ss = 0.f, vs1 = 0.f, vs2 = 0.f;
#pragma unroll
  for (int r = 0; r < 16; ++r) {
    int o = 32*wv + (r&3) + 8*(r>>2) + 4*hi;
    float4 iw = *(const float4*)(img_w + o*4);
    float de = iw.x*d0 + iw.y*d1 + iw.z*d2 + iw.w*d3 - c_embed[bn*128 + o];
    ime[r] = de; ss += de*de;
    float vv = accv[r];
    vs1 += vv; vs2 += vv*vv;
  }
  ss  += __shfl_xor(ss, 32);
  vs1 += __shfl_xor(vs1, 32);
  vs2 += __shfl_xor(vs2, 32);
  if (hi == 0) { sRed[0][wv][lo] = ss; sRed[1][wv][lo] = vs1; sRed[2][wv][lo] = vs2; }
  __syncthreads();
  float sst  = sRed[0][0][lo]+sRed[0][1][lo]+sRed[0][2][lo]+sRed[0][3][lo];
  float vs1t = sRed[1][0][lo]+sRed[1][1][lo]+sRed[1][2][lo]+sRed[1][3][lo];
  float vs2t = sRed[2][0][lo]+sRed[2][1][lo]+sRed[2][2][lo]+sRed[2][3][lo];
  float rinv = 1.f/(sqrtf(sst) + 1e-7f);
  float vmu = vs1t*(1.f/128.f);
  float vrs = rsqrtf(vs2t*(1.f/128.f) - vmu*vmu + EPSF);

  float kval[16];
  float ks1 = 0.f, ks2 = 0.f;
#pragma unroll
  for (int r = 0; r < 16; ++r) {
    float kv2 = acck[r] + ime[r]*rinv;
    kval[r] = kv2; ks1 += kv2; ks2 += kv2*kv2;
  }
  ks1 += __shfl_xor(ks1, 32);
  ks2 += __shfl_xor(ks2, 32);
  if (hi == 0) { sRed[3][wv][lo] = ks1; sRed[4][wv][lo] = ks2; }
  __syncthreads();
  float ks1t = sRed[3][0][lo]+sRed[3][1][lo]+sRed[3][2][lo]+sRed[3][3][lo];
  float ks2t = sRed[4][0][lo]+sRed[4][1][lo]+sRed[4][2][lo]+sRed[4][3][lo];
  float kmu = ks1t*(1.f/128.f);
  float krs = rsqrtf(ks2t*(1.f/128.f) - kmu*kmu + EPSF);

  {
    int swz = (lo & 7) << 3;
#pragma unroll
    for (int g = 0; g < 4; ++g) {
      int ob = 32*wv + 8*g + 4*hi;
      float4 kg = *(const float4*)(k_ln_g + ob);
      float4 kb2 = *(const float4*)(k_ln_b + ob);
      float4 vg = *(const float4*)(v_ln_g + ob);
      float4 vb2 = *(const float4*)(v_ln_b + ob);
      float kn0 = (kval[4*g+0]-kmu)*krs*kg.x + kb2.x;
      float kn1 = (kval[4*g+1]-kmu)*krs*kg.y + kb2.y;
      float kn2 = (kval[4*g+2]-kmu)*krs*kg.z + kb2.z;
      float kn3 = (kval[4*g+3]-kmu)*krs*kg.w + kb2.w;
      float vn0 = (accv[4*g+0]-vmu)*vrs*vg.x + vb2.x;
      float vn1 = (accv[4*g+1]-vmu)*vrs*vg.y + vb2.y;
      float vn2 = (accv[4*g+2]-vmu)*vrs*vg.z + vb2.z;
      float vn3 = (accv[4*g+3]-vmu)*vrs*vg.w + vb2.w;
      int idx = lo*128 + (ob ^ swz);
      *(ushort4*)&sA[0][idx] = make_ushort4(f2bf(kn0), f2bf(kn1), f2bf(kn2), f2bf(kn3));
      *(ushort4*)&sA[1][idx] = make_ushort4(f2bf(vn0), f2bf(vn1), f2bf(vn2), f2bf(vn3));
    }
  }
  __syncthreads();

  f32x16 a2k = {}, a2v = {};
  {
    const unsigned short* wk = wp + WOFF_K + (32*wv + lo)*128 + hi*8;
    const unsigned short* wv2 = wp + WOFF_V + (32*wv + lo)*128 + hi*8;
    int swz = (lo & 7) << 3;
#pragma unroll
    for (int s = 0; s < 8; ++s) {
      int cbase = s*16 + hi*8;
      bf16x8 a0 = *(const bf16x8*)(wk + s*16);
      bf16x8 a1 = *(const bf16x8*)(wv2 + s*16);
      bf16x8 b0 = *(const bf16x8*)&sA[0][lo*128 + (cbase ^ swz)];
      bf16x8 b1 = *(const bf16x8*)&sA[1][lo*128 + (cbase ^ swz)];
      a2k = __builtin_amdgcn_mfma_f32_32x32x16_bf16(a0, b0, a2k, 0, 0, 0);
      a2v = __builtin_amdgcn_mfma_f32_32x32x16_bf16(a1, b1, a2v, 0, 0, 0);
    }
  }

  int pix = p0 + lo;
  if (pix < KPIX) {
    unsigned short* krow = khb + ((size_t)bn*KPIX + pix)*128;
#pragma unroll
    for (int g = 0; g < 4; ++g) {
      int ob = 32*wv + 8*g + 4*hi;
      float4 kb4 = *(const float4*)(k_b + ob);
      *(ushort4*)(krow + ob) = make_ushort4(
        f2bf(a2k[4*g+0] + kb4.x), f2bf(a2k[4*g+1] + kb4.y),
        f2bf(a2k[4*g+2] + kb4.z), f2bf(a2k[4*g+3] + kb4.w));
      float4 vb4 = *(const float4*)(v_b + ob);
      vtb[((size_t)bn*128 + ob+0)*KPIX + pix] = f2bf(a2v[4*g+0] + vb4.x);
      vtb[((size_t)bn*128 + ob+1)*KPIX + pix] = f2bf(a2v[4*g+1] + vb4.y);
      vtb[((size_t)bn*128 + ob+2)*KPIX + pix] = f2bf(a2v[4*g+2] + vb4.z);
      vtb[((size_t)bn*128 + ob+3)*KPIX + pix] = f2bf(a2v[4*g+3] + vb4.w);
    }
  }
}

// --- MFMA q (QKSCALE folded into prepacked weight + bias)
__global__ __launch_bounds__(256) void q_kernel(
    const float* __restrict__ x, const float* __restrict__ bev_grid,
    const float* __restrict__ bev_w, const float* __restrict__ bev_b,
    const float* __restrict__ c_embed,
    const float* __restrict__ q_ln_g, const float* __restrict__ q_ln_b,
    const float* __restrict__ q_b,
    const unsigned short* __restrict__ wp,
    unsigned short* __restrict__ qhb)
{
  int blk = blockIdx.x;
  int bn = blk >> 5, qt = blk & 31;
  int p0 = qt * 32;
  int b = bn / NN;
  int t = threadIdx.x;

  __shared__ unsigned short sQ[32*128];
  __shared__ float sRedQ[3][8][32];

  {
    int q = t & 31, og = t >> 5;
    int qi = p0 + q;
    float gx = bev_grid[qi], gy = bev_grid[QQ + qi];
    float be[16]; float ss = 0.f;
#pragma unroll
    for (int j = 0; j < 16; ++j) {
      int o = og*16 + j;
      float we = bev_w[o*2+0]*gx + bev_w[o*2+1]*gy + bev_b[o];
      float v = we - c_embed[bn*128 + o];
      be[j] = v; ss += v*v;
    }
    sRedQ[0][og][q] = ss;
    __syncthreads();
    float sst = 0.f;
#pragma unroll
    for (int g = 0; g < 8; ++g) sst += sRedQ[0][g][q];
    float rinv = 1.f/(sqrtf(sst) + 1e-7f);
    float s1 = 0.f, s2 = 0.f;
#pragma unroll
    for (int j = 0; j < 16; ++j) {
      int o = og*16 + j;
      float qv = be[j]*rinv + x[((size_t)(b*128 + o))*QQ + qi];
      be[j] = qv; s1 += qv; s2 += qv*qv;
    }
    sRedQ[1][og][q] = s1; sRedQ[2][og][q] = s2;
    __syncthreads();
    float s1t = 0.f, s2t = 0.f;
#pragma unroll
    for (int g = 0; g < 8; ++g) { s1t += sRedQ[1][g][q]; s2t += sRedQ[2][g][q]; }
    float mu = s1t*(1.f/128.f);
    float rs = rsqrtf(s2t*(1.f/128.f) - mu*mu + EPSF);
    int swz = (q & 7) << 3;
#pragma unroll
    for (int u = 0; u < 4; ++u) {
      int ob = og*16 + 4*u;
      float4 qg = *(const float4*)(q_ln_g + ob);
      float4 qb2 = *(const float4*)(q_ln_b + ob);
      *(ushort4*)&sQ[q*128 + (ob ^ swz)] = make_ushort4(
        f2bf((be[4*u+0]-mu)*rs*qg.x + qb2.x), f2bf((be[4*u+1]-mu)*rs*qg.y + qb2.y),
        f2bf((be[4*u+2]-mu)*rs*qg.z + qb2.z), f2bf((be[4*u+3]-mu)*rs*qg.w + qb2.w));
    }
  }
  __syncthreads();

  {
    int wvv = t >> 6, l = t & 63, lo = l & 31, hi = l >> 5;
    const unsigned short* wq = wp + WOFF_Q + (32*wvv + lo)*128 + hi*8;
    int swz = (lo & 7) << 3;
    f32x16 acc = {};
#pragma unroll
    for (int s = 0; s < 8; ++s) {
      int cbase = s*16 + hi*8;
      bf16x8 a0 = *(const bf16x8*)(wq + s*16);
      bf16x8 b0 = *(const bf16x8*)&sQ[lo*128 + (cbase ^ swz)];
      acc = __builtin_amdgcn_mfma_f32_32x32x16_bf16(a0, b0, acc, 0, 0, 0);
    }
    unsigned short* qrow = qhb + ((size_t)bn*QQ + p0 + lo)*128;
#pragma unroll
    for (int g = 0; g < 4; ++g) {
      int ob = 32*wvv + 8*g + 4*hi;
      float4 qb4 = *(const float4*)(q_b + ob);
      *(ushort4*)(qrow + ob) = make_ushort4(
        f2bf(acc[4*g+0] + qb4.x*QKSCALE), f2bf(acc[4*g+1] + qb4.y*QKSCALE),
        f2bf(acc[4*g+2] + qb4.z*QKSCALE), f2bf(acc[4*g+3] + qb4.w*QKSCALE));
    }
  }
}

// --- MFMA flash attention partials. block = (b, qt64, n, sp); wave = head, 64 q/block.
// Scores are in base-2 domain (log2e folded into q) -> native v_exp_f32.
__global__ __launch_bounds__(256) void attn_kernel(
    const unsigned short* __restrict__ qhb, const unsigned short* __restrict__ khb,
    const unsigned short* __restrict__ vtb,
    float* __restrict__ lsum, unsigned short* __restrict__ pacb)
{
  int blk = blockIdx.x;
  int sp = blk % SPLIT; blk /= SPLIT;
  int n  = blk % NN;    blk /= NN;
  int qt = blk % 16;    blk /= 16;
  int b  = blk;
  int t = threadIdx.x;
  int wave = t >> 6, l = t & 63, lo = l & 31, hi = l >> 5;
  int dho = wave * 32;
  int bn = b*NN + n;

  bf16x8 qf[2][2];
#pragma unroll
  for (int g = 0; g < 2; ++g) {
    const unsigned short* qrow = qhb + ((size_t)bn*QQ + qt*64 + g*32 + lo)*128 + dho + hi*8;
    qf[g][0] = *(const bf16x8*)(qrow);
    qf[g][1] = *(const bf16x8*)(qrow + 16);
  }

  f32x16 acc[2] = {};
  float lr[2] = {0.f, 0.f};

  int k0 = sp * KCHUNK, kend = k0 + KCHUNK;
  const unsigned short* kbase = khb + (size_t)bn*KPIX*128 + dho + hi*8;
  const unsigned short* vrow  = vtb + ((size_t)bn*128 + dho + lo)*KPIX;

  for (int K0 = k0; K0 < kend; K0 += 32) {
    const unsigned short* krow = kbase + (size_t)(K0 + lo)*128;
    bf16x8 kf0 = *(const bf16x8*)(krow);
    bf16x8 kf1 = *(const bf16x8*)(krow + 16);
    bf16x8 vf0 = *(const bf16x8*)(vrow + K0 + hi*8);
    bf16x8 vf1 = *(const bf16x8*)(vrow + K0 + 16 + hi*8);
    bool full = (K0 + 32 <= kend);
#pragma unroll
    for (int g = 0; g < 2; ++g) {
      f32x16 s = {};
      s = __builtin_amdgcn_mfma_f32_32x32x16_bf16(kf0, qf[g][0], s, 0, 0, 0);
      s = __builtin_amdgcn_mfma_f32_32x32x16_bf16(kf1, qf[g][1], s, 0, 0, 0);
      float p[16];
      float lsub = 0.f;
      if (full) {
#pragma unroll
        for (int r = 0; r < 16; ++r) { float e = fast_exp2(s[r]); p[r] = e; lsub += e; }
      } else {
#pragma unroll
        for (int r = 0; r < 16; ++r) {
          int key = K0 + (r&3) + 8*(r>>2) + 4*hi;
          float e = (key < kend) ? fast_exp2(s[r]) : 0.f;
          p[r] = e; lsub += e;
        }
      }
      lr[g] += lsub;
#pragma unroll
      for (int ks = 0; ks < 2; ++ks) {
        int rb = ks*8;
        unsigned a0 = pk_bf16(p[rb+0], p[rb+1]);
        unsigned c0 = pk_bf16(p[rb+2], p[rb+3]);
        unsigned b0 = pk_bf16(p[rb+4], p[rb+5]);
        unsigned d0 = pk_bf16(p[rb+6], p[rb+7]);
        half_swap(a0, b0);
        half_swap(c0, d0);
        union { unsigned u[4]; bf16x8 v; } pa;
        pa.u[0] = a0; pa.u[1] = c0; pa.u[2] = b0; pa.u[3] = d0;
        acc[g] = __builtin_amdgcn_mfma_f32_32x32x16_bf16(pa.v, ks ? vf1 : vf0, acc[g], 0, 0, 0);
      }
    }
  }

  size_t hb = ((size_t)(b*4 + wave)*NPART + (n*SPLIT + sp))*QQ;
#pragma unroll
  for (int g = 0; g < 2; ++g) {
    float ltot = lr[g] + __shfl_xor(lr[g], 32);
    if (hi == 0) lsum[hb + qt*64 + g*32 + lo] = ltot;
#pragma unroll
    for (int r = 0; r < 16; ++r) {
      int crow = (r&3) + 8*(r>>2) + 4*hi;
      pacb[(hb + qt*64 + g*32 + crow)*32 + lo] = f2bf(acc[g][r]);
    }
  }
}

// --- MFMA epilogue: combine + proj + skip + preLN + MLP(gelu) + postLN + store.
__global__ __launch_bounds__(512) void epi_kernel(
    const float* __restrict__ lsum, const unsigned short* __restrict__ pacb,
    const float* __restrict__ x, const unsigned short* __restrict__ wp,
    const float* __restrict__ proj_b,
    const float* __restrict__ pre_g, const float* __restrict__ pre_b,
    const float* __restrict__ mlp_b1, const float* __restrict__ mlp_b2,
    const float* __restrict__ post_g, const float* __restrict__ post_b,
    float* __restrict__ out)
{
  int blk = blockIdx.x;
  int b = blk >> 5, qt = blk & 31;
  int q0 = qt * 32;
  int t = threadIdx.x;
  int wv = t >> 6, l = t & 63, lo = l & 31, hi = l >> 5;
  int rt = wv & 3, kh = wv >> 2;

  __shared__ unsigned short sA[32*128];
  __shared__ unsigned short sZ[32*128];
  __shared__ unsigned short sH[32*256];
  __shared__ float sPar[4][64][16];
  __shared__ float sRedE[2][4][32];

  {
    int q = t & 31, g = t >> 5;              // g 0..15
    int m = g >> 2, dl = (g & 3) * 8;
    size_t basehm = ((size_t)(b*4 + m)*NPART)*QQ + q0 + q;
    float lt = 0.f;
    float av[8] = {0,0,0,0,0,0,0,0};
    for (int j = 0; j < NPART; ++j) {
      size_t base = basehm + (size_t)j*QQ;
      lt += lsum[base];
      const unsigned short* pp = pacb + base*32 + dl;
      ushort4 u0 = *(const ushort4*)(pp);
      ushort4 u1 = *(const ushort4*)(pp + 4);
      av[0] += bf2f(u0.x); av[1] += bf2f(u0.y); av[2] += bf2f(u0.z); av[3] += bf2f(u0.w);
      av[4] += bf2f(u1.x); av[5] += bf2f(u1.y); av[6] += bf2f(u1.z); av[7] += bf2f(u1.w);
    }
    float rl = 1.f / lt;
    int swz = (q & 7) << 3;
    int dg = (g*8) ^ swz;
    *(ushort4*)&sA[q*128 + dg] = make_ushort4(
      f2bf(av[0]*rl), f2bf(av[1]*rl), f2bf(av[2]*rl), f2bf(av[3]*rl));
    *(ushort4*)&sA[q*128 + dg + 4] = make_ushort4(
      f2bf(av[4]*rl), f2bf(av[5]*rl), f2bf(av[6]*rl), f2bf(av[7]*rl));
  }
  __syncthreads();

  f32x16 acc = {};
  {
    const unsigned short* wA = wp + WOFF_PROJ + (32*rt + lo)*128 + kh*64 + hi*8;
    int swz = (lo & 7) << 3;
#pragma unroll
    for (int s = 0; s < 4; ++s) {
      int cb = kh*64 + s*16 + hi*8;
      bf16x8 a0 = *(const bf16x8*)(wA + s*16);
      bf16x8 b0 = *(const bf16x8*)&sA[lo*128 + (cb ^ swz)];
      acc = __builtin_amdgcn_mfma_f32_32x32x16_bf16(a0, b0, acc, 0, 0, 0);
    }
  }
  if (wv >= 4) {
#pragma unroll
    for (int r = 0; r < 16; ++r) sPar[wv-4][l][r] = acc[r];
  }
  __syncthreads();

  float znr[16], zv[16];
  if (wv < 4) {
    float s1 = 0.f, s2 = 0.f;
#pragma unroll
    for (int r = 0; r < 16; ++r) {
      int o = 32*rt + (r&3) + 8*(r>>2) + 4*hi;
      float z = acc[r] + sPar[wv][l][r] + proj_b[o] + x[((size_t)b*128 + o)*QQ + q0 + lo];
      zv[r] = z; s1 += z; s2 += z*z;
    }
    s1 += __shfl_xor(s1, 32); s2 += __shfl_xor(s2, 32);
    if (hi == 0) { sRedE[0][rt][lo] = s1; sRedE[1][rt][lo] = s2; }
  }
  __syncthreads();
  if (wv < 4) {
    float s1t = sRedE[0][0][lo]+sRedE[0][1][lo]+sRedE[0][2][lo]+sRedE[0][3][lo];
    float s2t = sRedE[1][0][lo]+sRedE[1][1][lo]+sRedE[1][2][lo]+sRedE[1][3][lo];
    float mu = s1t*(1.f/128.f);
    float rs = rsqrtf(s2t*(1.f/128.f) - mu*mu + EPSF);
    int swz = (lo & 7) << 3;
#pragma unroll
    for (int g2 = 0; g2 < 4; ++g2) {
      int ob = 32*rt + 8*g2 + 4*hi;
      float4 pg = *(const float4*)(pre_g + ob);
      float4 pb = *(const float4*)(pre_b + ob);
      float z0 = (zv[4*g2+0]-mu)*rs*pg.x + pb.x;
      float z1 = (zv[4*g2+1]-mu)*rs*pg.y + pb.y;
      float z2 = (zv[4*g2+2]-mu)*rs*pg.z + pb.z;
      float z3 = (zv[4*g2+3]-mu)*rs*pg.w + pb.w;
      znr[4*g2+0] = z0; znr[4*g2+1] = z1; znr[4*g2+2] = z2; znr[4*g2+3] = z3;
      *(ushort4*)&sZ[lo*128 + (ob ^ swz)] = make_ushort4(f2bf(z0), f2bf(z1), f2bf(z2), f2bf(z3));
    }
  }
  __syncthreads();

  {
    f32x16 acch = {};
    const unsigned short* wA = wp + WOFF_W1 + (32*wv + lo)*128 + hi*8;
    int swz = (lo & 7) << 3;
#pragma unroll
    for (int s = 0; s < 8; ++s) {
      int cb = s*16 + hi*8;
      bf16x8 a0 = *(const bf16x8*)(wA + s*16);
      bf16x8 b0 = *(const bf16x8*)&sZ[lo*128 + (cb ^ swz)];
      acch = __builtin_amdgcn_mfma_f32_32x32x16_bf16(a0, b0, acch, 0, 0, 0);
    }
#pragma unroll
    for (int g2 = 0; g2 < 4; ++g2) {
      int hrow = 32*wv + 8*g2 + 4*hi;
      float4 b1 = *(const float4*)(mlp_b1 + hrow);
      float h0 = acch[4*g2+0] + b1.x, h1 = acch[4*g2+1] + b1.y;
      float h2 = acch[4*g2+2] + b1.z, h3 = acch[4*g2+3] + b1.w;
      float g0 = 0.5f*h0*(1.f + erff(h0*0.7071067811865476f));
      float g1 = 0.5f*h1*(1.f + erff(h1*0.7071067811865476f));
      float g2f = 0.5f*h2*(1.f + erff(h2*0.7071067811865476f));
      float g3 = 0.5f*h3*(1.f + erff(h3*0.7071067811865476f));
      *(ushort4*)&sH[lo*256 + (hrow ^ swz)] = make_ushort4(f2bf(g0), f2bf(g1), f2bf(g2f), f2bf(g3));
    }
  }
  __syncthreads();

  f32x16 acc2 = {};
  {
    const unsigned short* wA = wp + WOFF_W2 + (32*rt + lo)*256 + kh*128 + hi*8;
    int swz = (lo & 7) << 3;
#pragma unroll
    for (int s = 0; s < 8; ++s) {
      int cb = kh*128 + s*16 + hi*8;
      bf16x8 a0 = *(const bf16x8*)(wA + s*16);
      bf16x8 b0 = *(const bf16x8*)&sH[lo*256 + (cb ^ swz)];
      acc2 = __builtin_amdgcn_mfma_f32_32x32x16_bf16(a0, b0, acc2, 0, 0, 0);
    }
  }
  if (wv >= 4) {
#pragma unroll
    for (int r = 0; r < 16; ++r) sPar[wv-4][l][r] = acc2[r];
  }
  __syncthreads();

  float z2v[16];
  if (wv < 4) {
    float s1 = 0.f, s2 = 0.f;
#pragma unroll
    for (int r = 0; r < 16; ++r) {
      int o = 32*rt + (r&3) + 8*(r>>2) + 4*hi;
      float z2 = znr[r] + acc2[r] + sPar[wv][l][r] + mlp_b2[o];
      z2v[r] = z2; s1 += z2; s2 += z2*z2;
    }
    s1 += __shfl_xor(s1, 32); s2 += __shfl_xor(s2, 32);
    if (hi == 0) { sRedE[0][rt][lo] = s1; sRedE[1][rt][lo] = s2; }
  }
  __syncthreads();
  if (wv < 4) {
    float s1t = sRedE[0][0][lo]+sRedE[0][1][lo]+sRedE[0][2][lo]+sRedE[0][3][lo];
    float s2t = sRedE[1][0][lo]+sRedE[1][1][lo]+sRedE[1][2][lo]+sRedE[1][3][lo];
    float mu = s1t*(1.f/128.f);
    float rs = rsqrtf(s2t*(1.f/128.f) - mu*mu + EPSF);
#pragma unroll
    for (int r = 0; r < 16; ++r) {
      int o = 32*rt + (r&3) + 8*(r>>2) + 4*hi;
      out[((size_t)b*128 + o)*QQ + q0 + lo] = (z2v[r]-mu)*rs*post_g[o] + post_b[o];
    }
  }
}

extern "C" void kernel_launch(void* const* d_in, const int* in_sizes, int n_in,
                              void* d_out, int out_size, void* d_ws, size_t ws_size,
                              hipStream_t stream) {
  const float* x           = (const float*)d_in[0];
  const float* feature     = (const float*)d_in[1];
  const float* I_inv       = (const float*)d_in[2];
  const float* E_inv       = (const float*)d_in[3];
  const float* bev_grid    = (const float*)d_in[4];
  const float* image_plane = (const float*)d_in[5];
  const float* fl_bn_g = (const float*)d_in[6];
  const float* fl_bn_b = (const float*)d_in[7];
  const float* fl_bn_m = (const float*)d_in[8];
  const float* fl_bn_v = (const float*)d_in[9];
  const float* fl_w    = (const float*)d_in[10];
  const float* fp_bn_g = (const float*)d_in[11];
  const float* fp_bn_b = (const float*)d_in[12];
  const float* fp_bn_m = (const float*)d_in[13];
  const float* fp_bn_v = (const float*)d_in[14];
  const float* fp_w    = (const float*)d_in[15];
  const float* bev_w   = (const float*)d_in[16];
  const float* bev_b   = (const float*)d_in[17];
  const float* img_w   = (const float*)d_in[18];
  const float* cam_w   = (const float*)d_in[19];
  const float* q_ln_g  = (const float*)d_in[20];
  const float* q_ln_b  = (const float*)d_in[21];
  const float* q_w     = (const float*)d_in[22];
  const float* q_b     = (const float*)d_in[23];
  const float* k_ln_g  = (const float*)d_in[24];
  const float* k_ln_b  = (const float*)d_in[25];
  const float* k_w     = (const float*)d_in[26];
  const float* k_b     = (const float*)d_in[27];
  const float* v_ln_g  = (const float*)d_in[28];
  const float* v_ln_b  = (const float*)d_in[29];
  const float* v_w     = (const float*)d_in[30];
  const float* v_b     = (const float*)d_in[31];
  const float* proj_w  = (const float*)d_in[32];
  const float* proj_b  = (const float*)d_in[33];
  const float* pre_g   = (const float*)d_in[34];
  const float* pre_b   = (const float*)d_in[35];
  const float* mlp_w1  = (const float*)d_in[36];
  const float* mlp_b1  = (const float*)d_in[37];
  const float* mlp_w2  = (const float*)d_in[38];
  const float* mlp_b2  = (const float*)d_in[39];
  const float* post_g  = (const float*)d_in[40];
  const float* post_b  = (const float*)d_in[41];

  // ws layout: f32 first, then bf16 (all 16B aligned)
  float* ws = (float*)d_ws;
  float* c_embed = ws;                                         // 1536 f32
  float* lsum = ws + 1536;                                     // BB*4*NPART*QQ f32
  unsigned short* pacb = (unsigned short*)(lsum + (size_t)BB*4*NPART*QQ);
  unsigned short* qhb = pacb + (size_t)BB*4*NPART*QQ*32;       // bf16
  unsigned short* khb = qhb + (size_t)BB*NN*QQ*128;
  unsigned short* vtb = khb + (size_t)BB*NN*KPIX*128;
  unsigned short* wpk = vtb + (size_t)BB*NN*KPIX*128;          // WPK_ELEMS bf16
  float* out = (float*)d_out;

  hipLaunchKernelGGL(prepack_kernel, dim3(1280), dim3(128), 0, stream,
                     fp_w, fl_w, k_w, v_w, q_w, proj_w, mlp_w1, mlp_w2, wpk);
  hipLaunchKernelGGL(ce_kernel, dim3(BB*NN), dim3(128), 0, stream, cam_w, E_inv, c_embed);
  hipLaunchKernelGGL(kv_kernel, dim3(BB*NN*NTILE_KV), dim3(256), 0, stream,
                     feature, I_inv, E_inv, image_plane, c_embed, img_w,
                     fp_bn_g, fp_bn_b, fp_bn_m, fp_bn_v,
                     fl_bn_g, fl_bn_b, fl_bn_m, fl_bn_v,
                     k_ln_g, k_ln_b, k_b,
                     v_ln_g, v_ln_b, v_b,
                     wpk, khb, vtb);
  hipLaunchKernelGGL(q_kernel, dim3(BB*NN*32), dim3(256), 0, stream,
                     x, bev_grid, bev_w, bev_b, c_embed,
                     q_ln_g, q_ln_b, q_b, wpk, qhb);
  hipLaunchKernelGGL(attn_kernel, dim3(BB*16*NN*SPLIT), dim3(256), 0, stream,
                     qhb, khb, vtb, lsum, pacb);
  hipLaunchKernelGGL(epi_kernel, dim3(BB*32), dim3(512), 0, stream,
                     lsum, pacb, x, wpk, proj_b, pre_g, pre_b,
                     mlp_b1, mlp_b2, post_g, post_b, out);
}

// Round 9
// 86.824 us; speedup vs baseline: 1.0146x; 1.0146x over previous
//
#include <hip/hip_runtime.h>
#include <math.h>

#define EPSF 1e-5f

// problem sizes
#define BB 2
#define NN 6
#define KPIX 1680      // 28*60
#define QQ 1024        // 32*32
#define SPLIT 6
#define KCHUNK (KPIX/SPLIT)   // 280
#define NPART (NN*SPLIT)      // 36
#define QKSCALE (0.17677669529663687f * 1.4426950408889634f)  // 32^-0.5 * log2(e)
#define NTILE_KV 53    // ceil(1680/32)
#define KVGRID (BB*NN*NTILE_KV)   // 636

// prepacked weight offsets (bf16 elements)
#define WOFF_FP   0
#define WOFF_FL   16384
#define WOFF_K    32768
#define WOFF_V    49152
#define WOFF_Q    65536
#define WOFF_PROJ 81920
#define WOFF_W1   98304
#define WOFF_W2   131072
#define WPK_ELEMS 163840

typedef __attribute__((ext_vector_type(8))) short bf16x8;
typedef __attribute__((ext_vector_type(16))) float f32x16;

__device__ __forceinline__ unsigned short f2bf(float f) {
  union { float f; unsigned u; } v; v.f = f;
  unsigned r = v.u + 0x7FFFu + ((v.u >> 16) & 1u);   // RNE
  return (unsigned short)(r >> 16);
}
__device__ __forceinline__ float bf2f(unsigned short u) {
  union { unsigned u; float f; } v; v.u = ((unsigned)u) << 16; return v.f;
}
__device__ __forceinline__ unsigned pk_bf16(float lo, float hi) {
  unsigned r;
  asm volatile("v_cvt_pk_bf16_f32 %0, %1, %2" : "=v"(r) : "v"(lo), "v"(hi));
  return r;
}
__device__ __forceinline__ float fast_exp2(float x) {
  return __builtin_amdgcn_exp2f(x);   // native v_exp_f32 (base-2)
}
// half_swap: exchange 32-lane halves between a and b
__device__ __forceinline__ void half_swap(unsigned &a, unsigned &b) {
#if __has_builtin(__builtin_amdgcn_permlane32_swap)
  auto r = __builtin_amdgcn_permlane32_swap(a, b, false, false);
  a = (unsigned)r[0]; b = (unsigned)r[1];
#else
  unsigned sa = (unsigned)__shfl_xor((int)a, 32);
  unsigned sb = (unsigned)__shfl_xor((int)b, 32);
  int hi = (threadIdx.x & 63) >> 5;
  unsigned na = hi ? sb : a;
  unsigned nb = hi ? b : sa;
  a = na; b = nb;
#endif
}

// --- fused: weight prepack (blocks 0..1279) + camera-center embed (blocks 1280..1291)
__global__ void pre_kernel(const float* __restrict__ fp_w, const float* __restrict__ fl_w,
                           const float* __restrict__ k_w, const float* __restrict__ v_w,
                           const float* __restrict__ q_w, const float* __restrict__ proj_w,
                           const float* __restrict__ mlp_w1, const float* __restrict__ mlp_w2,
                           const float* __restrict__ cam_w, const float* __restrict__ E_inv,
                           unsigned short* __restrict__ wp, float* __restrict__ c_embed) {
  int blk = blockIdx.x;
  int c = threadIdx.x;
  if (blk < 640) {
    int mat = blk >> 7, o = blk & 127;
    float v;
    if (mat == 0)      v = fp_w[o*128 + c];
    else if (mat == 1) v = fl_w[o*128 + c];
    else if (mat == 2) v = k_w[c*128 + o];
    else if (mat == 3) v = v_w[c*128 + o];
    else               v = q_w[c*128 + o] * QKSCALE;
    wp[(size_t)mat*16384 + o*128 + c] = f2bf(v);
  } else if (blk < 768) {
    int row = blk - 640;                         // proj^T [o][i]
    wp[WOFF_PROJ + row*128 + c] = f2bf(proj_w[c*128 + row]);
  } else if (blk < 1024) {
    int row = blk - 768;                         // w1^T [h][i]
    wp[WOFF_W1 + row*128 + c] = f2bf(mlp_w1[c*256 + row]);
  } else if (blk < 1280) {
    int i2 = blk - 1024;                         // w2^T [o][h]
    int row = i2 >> 1, col = (i2 & 1)*128 + c;
    wp[WOFF_W2 + row*256 + col] = f2bf(mlp_w2[col*128 + row]);
  } else {
    int bn = blk - 1280;
    const float* E = E_inv + bn * 16;
    float s = cam_w[c*4+0]*E[3] + cam_w[c*4+1]*E[7] + cam_w[c*4+2]*E[11] + cam_w[c*4+3]*E[15];
    c_embed[bn*128 + c] = s;
  }
}

// --- fused projection kernel: blocks [0,KVGRID) = kv path, [KVGRID, +384) = q path.
// kv: round-4/5 replay-stable 4-wave structure, with ushort2-packed LDS staging.
__global__ __launch_bounds__(256) void proj_kernel(
    const float* __restrict__ feature, const float* __restrict__ I_inv,
    const float* __restrict__ E_inv, const float* __restrict__ image_plane,
    const float* __restrict__ c_embed, const float* __restrict__ img_w,
    const float* __restrict__ fp_bn_g, const float* __restrict__ fp_bn_b,
    const float* __restrict__ fp_bn_m, const float* __restrict__ fp_bn_v,
    const float* __restrict__ fl_bn_g, const float* __restrict__ fl_bn_b,
    const float* __restrict__ fl_bn_m, const float* __restrict__ fl_bn_v,
    const float* __restrict__ k_ln_g, const float* __restrict__ k_ln_b,
    const float* __restrict__ k_b,
    const float* __restrict__ v_ln_g, const float* __restrict__ v_ln_b,
    const float* __restrict__ v_b,
    const float* __restrict__ x, const float* __restrict__ bev_grid,
    const float* __restrict__ bev_w, const float* __restrict__ bev_b,
    const float* __restrict__ q_ln_g, const float* __restrict__ q_ln_b,
    const float* __restrict__ q_b,
    const unsigned short* __restrict__ wp,
    unsigned short* __restrict__ khb, unsigned short* __restrict__ vtb,
    unsigned short* __restrict__ qhb)
{
  __shared__ __align__(16) unsigned char smem[19456];
  int t = threadIdx.x;

  if (blockIdx.x < KVGRID) {
    // ================= KV path =================
    unsigned short (*sA)[32*128] = reinterpret_cast<unsigned short(*)[32*128]>(smem);
    float (*sD)[32]     = reinterpret_cast<float(*)[32]>(smem + 16384);
    float (*sRed)[4][32] = reinterpret_cast<float(*)[4][32]>(smem + 16384 + 512);

    int blk = blockIdx.x;
    int bn = blk / NTILE_KV, tp = blk % NTILE_KV;
    int p0 = tp * 32;
    int wv = t >> 6, l = t & 63, lo = l & 31, hi = l >> 5;

    if (t < 32) {
      int pix = min(p0 + t, KPIX-1);
      const float* Ii = I_inv + bn*9;
      const float* Ei = E_inv + bn*16;
      float px = image_plane[pix], py = image_plane[KPIX + pix], pz = image_plane[2*KPIX + pix];
      float c0 = Ii[0]*px + Ii[1]*py + Ii[2]*pz;
      float c1 = Ii[3]*px + Ii[4]*py + Ii[5]*pz;
      float c2 = Ii[6]*px + Ii[7]*py + Ii[8]*pz;
      sD[0][t] = Ei[0]*c0 + Ei[1]*c1 + Ei[2]*c2  + Ei[3];
      sD[1][t] = Ei[4]*c0 + Ei[5]*c1 + Ei[6]*c2  + Ei[7];
      sD[2][t] = Ei[8]*c0 + Ei[9]*c1 + Ei[10]*c2 + Ei[11];
      sD[3][t] = Ei[12]*c0 + Ei[13]*c1 + Ei[14]*c2 + Ei[15];
    }

    // staging: thread = (path, channel-pair, pixel-half); ushort2 LDS writes
    {
      int path = t >> 7;            // 0 = fp(K), 1 = fl(V)
      int cp = (t >> 1) & 63;
      int ph = t & 1;
      int c0 = cp * 2;
      const float* bg = path ? fl_bn_g : fp_bn_g;
      const float* bb = path ? fl_bn_b : fp_bn_b;
      const float* bm = path ? fl_bn_m : fp_bn_m;
      const float* bv = path ? fl_bn_v : fp_bn_v;
      float g0 = bg[c0+0]*rsqrtf(bv[c0+0]+EPSF); float o0 = bb[c0+0] - bm[c0+0]*g0;
      float g1 = bg[c0+1]*rsqrtf(bv[c0+1]+EPSF); float o1 = bb[c0+1] - bm[c0+1]*g1;
      const float* frow0 = feature + ((size_t)bn*128 + c0)*KPIX;
      const float* frow1 = frow0 + KPIX;
#pragma unroll
      for (int i = 0; i < 4; ++i) {
        int plb = ph*16 + 4*i;
        int pix = p0 + plb;
        float4 f0, f1;
        if (pix + 3 < KPIX) {
          f0 = *(const float4*)(frow0 + pix);
          f1 = *(const float4*)(frow1 + pix);
        } else {
          f0.x = frow0[min(pix+0, KPIX-1)]; f0.y = frow0[min(pix+1, KPIX-1)];
          f0.z = frow0[min(pix+2, KPIX-1)]; f0.w = frow0[min(pix+3, KPIX-1)];
          f1.x = frow1[min(pix+0, KPIX-1)]; f1.y = frow1[min(pix+1, KPIX-1)];
          f1.z = frow1[min(pix+2, KPIX-1)]; f1.w = frow1[min(pix+3, KPIX-1)];
        }
        float fa[4] = {f0.x, f0.y, f0.z, f0.w};
        float fb[4] = {f1.x, f1.y, f1.z, f1.w};
#pragma unroll
        for (int j = 0; j < 4; ++j) {
          int pl = plb + j;
          int cc = c0 ^ ((pl & 7) << 3);   // XOR hits bits>=3 only: pair stays adjacent
          ushort2 w;
          w.x = f2bf(fmaxf(fa[j]*g0 + o0, 0.f));
          w.y = f2bf(fmaxf(fb[j]*g1 + o1, 0.f));
          *(ushort2*)&sA[path][pl*128 + cc] = w;
        }
      }
    }
    __syncthreads();

    f32x16 acck = {}, accv = {};
    {
      const unsigned short* wfp = wp + WOFF_FP + (32*wv + lo)*128 + hi*8;
      const unsigned short* wfl = wp + WOFF_FL + (32*wv + lo)*128 + hi*8;
      int swz = (lo & 7) << 3;
#pragma unroll
      for (int s = 0; s < 8; ++s) {
        int cbase = s*16 + hi*8;
        bf16x8 a0 = *(const bf16x8*)(wfp + s*16);
        bf16x8 a1 = *(const bf16x8*)(wfl + s*16);
        bf16x8 b0 = *(const bf16x8*)&sA[0][lo*128 + (cbase ^ swz)];
        bf16x8 b1 = *(const bf16x8*)&sA[1][lo*128 + (cbase ^ swz)];
        acck = __builtin_amdgcn_mfma_f32_32x32x16_bf16(a0, b0, acck, 0, 0, 0);
        accv = __builtin_amdgcn_mfma_f32_32x32x16_bf16(a1, b1, accv, 0, 0, 0);
      }
    }

    float d0 = sD[0][lo], d1 = sD[1][lo], d2 = sD[2][lo], d3 = sD[3][lo];

    float ime[16];
    float ss = 0.f, vs1 = 0.f, vs2 = 0.f;
#pragma unroll
    for (int r = 0; r < 16; ++r) {
      int o = 32*wv + (r&3) + 8*(r>>2) + 4*hi;
      float4 iw = *(const float4*)(img_w + o*4);
      float de = iw.x*d0 + iw.y*d1 + iw.z*d2 + iw.w*d3 - c_embed[bn*128 + o];
      ime[r] = de; ss += de*de;
      float vv = accv[r];
      vs1 += vv; vs2 += vv*vv;
    }
    ss  += __shfl_xor(ss, 32);
    vs1 += __shfl_xor(vs1, 32);
    vs2 += __shfl_xor(vs2, 32);
    if (hi == 0) { sRed[0][wv][lo] = ss; sRed[1][wv][lo] = vs1; sRed[2][wv][lo] = vs2; }
    __syncthreads();
    float sst  = sRed[0][0][lo]+sRed[0][1][lo]+sRed[0][2][lo]+sRed[0][3][lo];
    float vs1t = sRed[1][0][lo]+sRed[1][1][lo]+sRed[1][2][lo]+sRed[1][3][lo];
    float vs2t = sRed[2][0][lo]+sRed[2][1][lo]+sRed[2][2][lo]+sRed[2][3][lo];
    float rinv = 1.f/(sqrtf(sst) + 1e-7f);
    float vmu = vs1t*(1.f/128.f);
    float vrs = rsqrtf(vs2t*(1.f/128.f) - vmu*vmu + EPSF);

    float kval[16];
    float ks1 = 0.f, ks2 = 0.f;
#pragma unroll
    for (int r = 0; r < 16; ++r) {
      float kv2 = acck[r] + ime[r]*rinv;
      kval[r] = kv2; ks1 += kv2; ks2 += kv2*kv2;
    }
    ks1 += __shfl_xor(ks1, 32);
    ks2 += __shfl_xor(ks2, 32);
    if (hi == 0) { sRed[3][wv][lo] = ks1; sRed[4][wv][lo] = ks2; }
    __syncthreads();
    float ks1t = sRed[3][0][lo]+sRed[3][1][lo]+sRed[3][2][lo]+sRed[3][3][lo];
    float ks2t = sRed[4][0][lo]+sRed[4][1][lo]+sRed[4][2][lo]+sRed[4][3][lo];
    float kmu = ks1t*(1.f/128.f);
    float krs = rsqrtf(ks2t*(1.f/128.f) - kmu*kmu + EPSF);

    {
      int swz = (lo & 7) << 3;
#pragma unroll
      for (int g = 0; g < 4; ++g) {
        int ob = 32*wv + 8*g + 4*hi;
        float4 kg = *(const float4*)(k_ln_g + ob);
        float4 kb2 = *(const float4*)(k_ln_b + ob);
        float4 vg = *(const float4*)(v_ln_g + ob);
        float4 vb2 = *(const float4*)(v_ln_b + ob);
        float kn0 = (kval[4*g+0]-kmu)*krs*kg.x + kb2.x;
        float kn1 = (kval[4*g+1]-kmu)*krs*kg.y + kb2.y;
        float kn2 = (kval[4*g+2]-kmu)*krs*kg.z + kb2.z;
        float kn3 = (kval[4*g+3]-kmu)*krs*kg.w + kb2.w;
        float vn0 = (accv[4*g+0]-vmu)*vrs*vg.x + vb2.x;
        float vn1 = (accv[4*g+1]-vmu)*vrs*vg.y + vb2.y;
        float vn2 = (accv[4*g+2]-vmu)*vrs*vg.z + vb2.z;
        float vn3 = (accv[4*g+3]-vmu)*vrs*vg.w + vb2.w;
        int idx = lo*128 + (ob ^ swz);
        *(ushort4*)&sA[0][idx] = make_ushort4(f2bf(kn0), f2bf(kn1), f2bf(kn2), f2bf(kn3));
        *(ushort4*)&sA[1][idx] = make_ushort4(f2bf(vn0), f2bf(vn1), f2bf(vn2), f2bf(vn3));
      }
    }
    __syncthreads();

    f32x16 a2k = {}, a2v = {};
    {
      const unsigned short* wk = wp + WOFF_K + (32*wv + lo)*128 + hi*8;
      const unsigned short* wv2 = wp + WOFF_V + (32*wv + lo)*128 + hi*8;
      int swz = (lo & 7) << 3;
#pragma unroll
      for (int s = 0; s < 8; ++s) {
        int cbase = s*16 + hi*8;
        bf16x8 a0 = *(const bf16x8*)(wk + s*16);
        bf16x8 a1 = *(const bf16x8*)(wv2 + s*16);
        bf16x8 b0 = *(const bf16x8*)&sA[0][lo*128 + (cbase ^ swz)];
        bf16x8 b1 = *(const bf16x8*)&sA[1][lo*128 + (cbase ^ swz)];
        a2k = __builtin_amdgcn_mfma_f32_32x32x16_bf16(a0, b0, a2k, 0, 0, 0);
        a2v = __builtin_amdgcn_mfma_f32_32x32x16_bf16(a1, b1, a2v, 0, 0, 0);
      }
    }

    int pix = p0 + lo;
    if (pix < KPIX) {
      unsigned short* krow = khb + ((size_t)bn*KPIX + pix)*128;
#pragma unroll
      for (int g = 0; g < 4; ++g) {
        int ob = 32*wv + 8*g + 4*hi;
        float4 kb4 = *(const float4*)(k_b + ob);
        *(ushort4*)(krow + ob) = make_ushort4(
          f2bf(a2k[4*g+0] + kb4.x), f2bf(a2k[4*g+1] + kb4.y),
          f2bf(a2k[4*g+2] + kb4.z), f2bf(a2k[4*g+3] + kb4.w));
        float4 vb4 = *(const float4*)(v_b + ob);
        vtb[((size_t)bn*128 + ob+0)*KPIX + pix] = f2bf(a2v[4*g+0] + vb4.x);
        vtb[((size_t)bn*128 + ob+1)*KPIX + pix] = f2bf(a2v[4*g+1] + vb4.y);
        vtb[((size_t)bn*128 + ob+2)*KPIX + pix] = f2bf(a2v[4*g+2] + vb4.z);
        vtb[((size_t)bn*128 + ob+3)*KPIX + pix] = f2bf(a2v[4*g+3] + vb4.w);
      }
    }
  } else {
    // ================= Q path =================
    unsigned short* sQ = reinterpret_cast<unsigned short*>(smem);
    float (*sRedQ)[8][32] = reinterpret_cast<float(*)[8][32]>(smem + 8192);

    int qblk = blockIdx.x - KVGRID;
    int bn = qblk >> 5, qt = qblk & 31;
    int p0 = qt * 32;
    int b = bn / NN;

    {
      int q = t & 31, og = t >> 5;
      int qi = p0 + q;
      float gx = bev_grid[qi], gy = bev_grid[QQ + qi];
      float be[16]; float ss = 0.f;
#pragma unroll
      for (int j = 0; j < 16; ++j) {
        int o = og*16 + j;
        float we = bev_w[o*2+0]*gx + bev_w[o*2+1]*gy + bev_b[o];
        float v = we - c_embed[bn*128 + o];
        be[j] = v; ss += v*v;
      }
      sRedQ[0][og][q] = ss;
      __syncthreads();
      float sst = 0.f;
#pragma unroll
      for (int g = 0; g < 8; ++g) sst += sRedQ[0][g][q];
      float rinv = 1.f/(sqrtf(sst) + 1e-7f);
      float s1 = 0.f, s2 = 0.f;
#pragma unroll
      for (int j = 0; j < 16; ++j) {
        int o = og*16 + j;
        float qv = be[j]*rinv + x[((size_t)(b*128 + o))*QQ + qi];
        be[j] = qv; s1 += qv; s2 += qv*qv;
      }
      sRedQ[1][og][q] = s1; sRedQ[2][og][q] = s2;
      __syncthreads();
      float s1t = 0.f, s2t = 0.f;
#pragma unroll
      for (int g = 0; g < 8; ++g) { s1t += sRedQ[1][g][q]; s2t += sRedQ[2][g][q]; }
      float mu = s1t*(1.f/128.f);
      float rs = rsqrtf(s2t*(1.f/128.f) - mu*mu + EPSF);
      int swz = (q & 7) << 3;
#pragma unroll
      for (int u = 0; u < 4; ++u) {
        int ob = og*16 + 4*u;
        float4 qg = *(const float4*)(q_ln_g + ob);
        float4 qb2 = *(const float4*)(q_ln_b + ob);
        *(ushort4*)&sQ[q*128 + (ob ^ swz)] = make_ushort4(
          f2bf((be[4*u+0]-mu)*rs*qg.x + qb2.x), f2bf((be[4*u+1]-mu)*rs*qg.y + qb2.y),
          f2bf((be[4*u+2]-mu)*rs*qg.z + qb2.z), f2bf((be[4*u+3]-mu)*rs*qg.w + qb2.w));
      }
    }
    __syncthreads();

    {
      int wvv = t >> 6, l = t & 63, lo = l & 31, hi = l >> 5;
      const unsigned short* wq = wp + WOFF_Q + (32*wvv + lo)*128 + hi*8;
      int swz = (lo & 7) << 3;
      f32x16 acc = {};
#pragma unroll
      for (int s = 0; s < 8; ++s) {
        int cbase = s*16 + hi*8;
        bf16x8 a0 = *(const bf16x8*)(wq + s*16);
        bf16x8 b0 = *(const bf16x8*)&sQ[lo*128 + (cbase ^ swz)];
        acc = __builtin_amdgcn_mfma_f32_32x32x16_bf16(a0, b0, acc, 0, 0, 0);
      }
      unsigned short* qrow = qhb + ((size_t)bn*QQ + p0 + lo)*128;
#pragma unroll
      for (int g = 0; g < 4; ++g) {
        int ob = 32*wvv + 8*g + 4*hi;
        float4 qb4 = *(const float4*)(q_b + ob);
        *(ushort4*)(qrow + ob) = make_ushort4(
          f2bf(acc[4*g+0] + qb4.x*QKSCALE), f2bf(acc[4*g+1] + qb4.y*QKSCALE),
          f2bf(acc[4*g+2] + qb4.z*QKSCALE), f2bf(acc[4*g+3] + qb4.w*QKSCALE));
      }
    }
  }
}

// --- MFMA flash attention partials. block = (b, qt64, n, sp); wave = head, 64 q/block.
// Scores are in base-2 domain (log2e folded into q) -> native v_exp_f32.
__global__ __launch_bounds__(256) void attn_kernel(
    const unsigned short* __restrict__ qhb, const unsigned short* __restrict__ khb,
    const unsigned short* __restrict__ vtb,
    float* __restrict__ lsum, unsigned short* __restrict__ pacb)
{
  int blk = blockIdx.x;
  int sp = blk % SPLIT; blk /= SPLIT;
  int n  = blk % NN;    blk /= NN;
  int qt = blk % 16;    blk /= 16;
  int b  = blk;
  int t = threadIdx.x;
  int wave = t >> 6, l = t & 63, lo = l & 31, hi = l >> 5;
  int dho = wave * 32;
  int bn = b*NN + n;

  bf16x8 qf[2][2];
#pragma unroll
  for (int g = 0; g < 2; ++g) {
    const unsigned short* qrow = qhb + ((size_t)bn*QQ + qt*64 + g*32 + lo)*128 + dho + hi*8;
    qf[g][0] = *(const bf16x8*)(qrow);
    qf[g][1] = *(const bf16x8*)(qrow + 16);
  }

  f32x16 acc[2] = {};
  float lr[2] = {0.f, 0.f};

  int k0 = sp * KCHUNK, kend = k0 + KCHUNK;
  const unsigned short* kbase = khb + (size_t)bn*KPIX*128 + dho + hi*8;
  const unsigned short* vrow  = vtb + ((size_t)bn*128 + dho + lo)*KPIX;

  for (int K0 = k0; K0 < kend; K0 += 32) {
    const unsigned short* krow = kbase + (size_t)(K0 + lo)*128;
    bf16x8 kf0 = *(const bf16x8*)(krow);
    bf16x8 kf1 = *(const bf16x8*)(krow + 16);
    bf16x8 vf0 = *(const bf16x8*)(vrow + K0 + hi*8);
    bf16x8 vf1 = *(const bf16x8*)(vrow + K0 + 16 + hi*8);
    bool full = (K0 + 32 <= kend);
#pragma unroll
    for (int g = 0; g < 2; ++g) {
      f32x16 s = {};
      s = __builtin_amdgcn_mfma_f32_32x32x16_bf16(kf0, qf[g][0], s, 0, 0, 0);
      s = __builtin_amdgcn_mfma_f32_32x32x16_bf16(kf1, qf[g][1], s, 0, 0, 0);
      float p[16];
      float lsub = 0.f;
      if (full) {
#pragma unroll
        for (int r = 0; r < 16; ++r) { float e = fast_exp2(s[r]); p[r] = e; lsub += e; }
      } else {
#pragma unroll
        for (int r = 0; r < 16; ++r) {
          int key = K0 + (r&3) + 8*(r>>2) + 4*hi;
          float e = (key < kend) ? fast_exp2(s[r]) : 0.f;
          p[r] = e; lsub += e;
        }
      }
      lr[g] += lsub;
#pragma unroll
      for (int ks = 0; ks < 2; ++ks) {
        int rb = ks*8;
        unsigned a0 = pk_bf16(p[rb+0], p[rb+1]);
        unsigned c0 = pk_bf16(p[rb+2], p[rb+3]);
        unsigned b0 = pk_bf16(p[rb+4], p[rb+5]);
        unsigned d0 = pk_bf16(p[rb+6], p[rb+7]);
        half_swap(a0, b0);
        half_swap(c0, d0);
        union { unsigned u[4]; bf16x8 v; } pa;
        pa.u[0] = a0; pa.u[1] = c0; pa.u[2] = b0; pa.u[3] = d0;
        acc[g] = __builtin_amdgcn_mfma_f32_32x32x16_bf16(pa.v, ks ? vf1 : vf0, acc[g], 0, 0, 0);
      }
    }
  }

  size_t hb = ((size_t)(b*4 + wave)*NPART + (n*SPLIT + sp))*QQ;
#pragma unroll
  for (int g = 0; g < 2; ++g) {
    float ltot = lr[g] + __shfl_xor(lr[g], 32);
    if (hi == 0) lsum[hb + qt*64 + g*32 + lo] = ltot;
#pragma unroll
    for (int r = 0; r < 16; ++r) {
      int crow = (r&3) + 8*(r>>2) + 4*hi;
      pacb[(hb + qt*64 + g*32 + crow)*32 + lo] = f2bf(acc[g][r]);
    }
  }
}

// --- MFMA epilogue: combine + proj + skip + preLN + MLP(gelu) + postLN + store.
__global__ __launch_bounds__(512) void epi_kernel(
    const float* __restrict__ lsum, const unsigned short* __restrict__ pacb,
    const float* __restrict__ x, const unsigned short* __restrict__ wp,
    const float* __restrict__ proj_b,
    const float* __restrict__ pre_g, const float* __restrict__ pre_b,
    const float* __restrict__ mlp_b1, const float* __restrict__ mlp_b2,
    const float* __restrict__ post_g, const float* __restrict__ post_b,
    float* __restrict__ out)
{
  int blk = blockIdx.x;
  int b = blk >> 5, qt = blk & 31;
  int q0 = qt * 32;
  int t = threadIdx.x;
  int wv = t >> 6, l = t & 63, lo = l & 31, hi = l >> 5;
  int rt = wv & 3, kh = wv >> 2;

  __shared__ unsigned short sA[32*128];
  __shared__ unsigned short sZ[32*128];
  __shared__ unsigned short sH[32*256];
  __shared__ float sPar[4][64][16];
  __shared__ float sRedE[2][4][32];

  {
    int q = t & 31, g = t >> 5;              // g 0..15
    int m = g >> 2, dl = (g & 3) * 8;
    size_t basehm = ((size_t)(b*4 + m)*NPART)*QQ + q0 + q;
    float lt = 0.f;
    float av[8] = {0,0,0,0,0,0,0,0};
    for (int j = 0; j < NPART; ++j) {
      size_t base = basehm + (size_t)j*QQ;
      lt += lsum[base];
      const unsigned short* pp = pacb + base*32 + dl;
      ushort4 u0 = *(const ushort4*)(pp);
      ushort4 u1 = *(const ushort4*)(pp + 4);
      av[0] += bf2f(u0.x); av[1] += bf2f(u0.y); av[2] += bf2f(u0.z); av[3] += bf2f(u0.w);
      av[4] += bf2f(u1.x); av[5] += bf2f(u1.y); av[6] += bf2f(u1.z); av[7] += bf2f(u1.w);
    }
    float rl = 1.f / lt;
    int swz = (q & 7) << 3;
    int dg = (g*8) ^ swz;
    *(ushort4*)&sA[q*128 + dg] = make_ushort4(
      f2bf(av[0]*rl), f2bf(av[1]*rl), f2bf(av[2]*rl), f2bf(av[3]*rl));
    *(ushort4*)&sA[q*128 + dg + 4] = make_ushort4(
      f2bf(av[4]*rl), f2bf(av[5]*rl), f2bf(av[6]*rl), f2bf(av[7]*rl));
  }
  __syncthreads();

  f32x16 acc = {};
  {
    const unsigned short* wA = wp + WOFF_PROJ + (32*rt + lo)*128 + kh*64 + hi*8;
    int swz = (lo & 7) << 3;
#pragma unroll
    for (int s = 0; s < 4; ++s) {
      int cb = kh*64 + s*16 + hi*8;
      bf16x8 a0 = *(const bf16x8*)(wA + s*16);
      bf16x8 b0 = *(const bf16x8*)&sA[lo*128 + (cb ^ swz)];
      acc = __builtin_amdgcn_mfma_f32_32x32x16_bf16(a0, b0, acc, 0, 0, 0);
    }
  }
  if (wv >= 4) {
#pragma unroll
    for (int r = 0; r < 16; ++r) sPar[wv-4][l][r] = acc[r];
  }
  __syncthreads();

  float znr[16], zv[16];
  if (wv < 4) {
    float s1 = 0.f, s2 = 0.f;
#pragma unroll
    for (int r = 0; r < 16; ++r) {
      int o = 32*rt + (r&3) + 8*(r>>2) + 4*hi;
      float z = acc[r] + sPar[wv][l][r] + proj_b[o] + x[((size_t)b*128 + o)*QQ + q0 + lo];
      zv[r] = z; s1 += z; s2 += z*z;
    }
    s1 += __shfl_xor(s1, 32); s2 += __shfl_xor(s2, 32);
    if (hi == 0) { sRedE[0][rt][lo] = s1; sRedE[1][rt][lo] = s2; }
  }
  __syncthreads();
  if (wv < 4) {
    float s1t = sRedE[0][0][lo]+sRedE[0][1][lo]+sRedE[0][2][lo]+sRedE[0][3][lo];
    float s2t = sRedE[1][0][lo]+sRedE[1][1][lo]+sRedE[1][2][lo]+sRedE[1][3][lo];
    float mu = s1t*(1.f/128.f);
    float rs = rsqrtf(s2t*(1.f/128.f) - mu*mu + EPSF);
    int swz = (lo & 7) << 3;
#pragma unroll
    for (int g2 = 0; g2 < 4; ++g2) {
      int ob = 32*rt + 8*g2 + 4*hi;
      float4 pg = *(const float4*)(pre_g + ob);
      float4 pb = *(const float4*)(pre_b + ob);
      float z0 = (zv[4*g2+0]-mu)*rs*pg.x + pb.x;
      float z1 = (zv[4*g2+1]-mu)*rs*pg.y + pb.y;
      float z2 = (zv[4*g2+2]-mu)*rs*pg.z + pb.z;
      float z3 = (zv[4*g2+3]-mu)*rs*pg.w + pb.w;
      znr[4*g2+0] = z0; znr[4*g2+1] = z1; znr[4*g2+2] = z2; znr[4*g2+3] = z3;
      *(ushort4*)&sZ[lo*128 + (ob ^ swz)] = make_ushort4(f2bf(z0), f2bf(z1), f2bf(z2), f2bf(z3));
    }
  }
  __syncthreads();

  {
    f32x16 acch = {};
    const unsigned short* wA = wp + WOFF_W1 + (32*wv + lo)*128 + hi*8;
    int swz = (lo & 7) << 3;
#pragma unroll
    for (int s = 0; s < 8; ++s) {
      int cb = s*16 + hi*8;
      bf16x8 a0 = *(const bf16x8*)(wA + s*16);
      bf16x8 b0 = *(const bf16x8*)&sZ[lo*128 + (cb ^ swz)];
      acch = __builtin_amdgcn_mfma_f32_32x32x16_bf16(a0, b0, acch, 0, 0, 0);
    }
#pragma unroll
    for (int g2 = 0; g2 < 4; ++g2) {
      int hrow = 32*wv + 8*g2 + 4*hi;
      float4 b1 = *(const float4*)(mlp_b1 + hrow);
      float h0 = acch[4*g2+0] + b1.x, h1 = acch[4*g2+1] + b1.y;
      float h2 = acch[4*g2+2] + b1.z, h3 = acch[4*g2+3] + b1.w;
      float g0 = 0.5f*h0*(1.f + erff(h0*0.7071067811865476f));
      float g1 = 0.5f*h1*(1.f + erff(h1*0.7071067811865476f));
      float g2f = 0.5f*h2*(1.f + erff(h2*0.7071067811865476f));
      float g3 = 0.5f*h3*(1.f + erff(h3*0.7071067811865476f));
      *(ushort4*)&sH[lo*256 + (hrow ^ swz)] = make_ushort4(f2bf(g0), f2bf(g1), f2bf(g2f), f2bf(g3));
    }
  }
  __syncthreads();

  f32x16 acc2 = {};
  {
    const unsigned short* wA = wp + WOFF_W2 + (32*rt + lo)*256 + kh*128 + hi*8;
    int swz = (lo & 7) << 3;
#pragma unroll
    for (int s = 0; s < 8; ++s) {
      int cb = kh*128 + s*16 + hi*8;
      bf16x8 a0 = *(const bf16x8*)(wA + s*16);
      bf16x8 b0 = *(const bf16x8*)&sH[lo*256 + (cb ^ swz)];
      acc2 = __builtin_amdgcn_mfma_f32_32x32x16_bf16(a0, b0, acc2, 0, 0, 0);
    }
  }
  if (wv >= 4) {
#pragma unroll
    for (int r = 0; r < 16; ++r) sPar[wv-4][l][r] = acc2[r];
  }
  __syncthreads();

  float z2v[16];
  if (wv < 4) {
    float s1 = 0.f, s2 = 0.f;
#pragma unroll
    for (int r = 0; r < 16; ++r) {
      int o = 32*rt + (r&3) + 8*(r>>2) + 4*hi;
      float z2 = znr[r] + acc2[r] + sPar[wv][l][r] + mlp_b2[o];
      z2v[r] = z2; s1 += z2; s2 += z2*z2;
    }
    s1 += __shfl_xor(s1, 32); s2 += __shfl_xor(s2, 32);
    if (hi == 0) { sRedE[0][rt][lo] = s1; sRedE[1][rt][lo] = s2; }
  }
  __syncthreads();
  if (wv < 4) {
    float s1t = sRedE[0][0][lo]+sRedE[0][1][lo]+sRedE[0][2][lo]+sRedE[0][3][lo];
    float s2t = sRedE[1][0][lo]+sRedE[1][1][lo]+sRedE[1][2][lo]+sRedE[1][3][lo];
    float mu = s1t*(1.f/128.f);
    float rs = rsqrtf(s2t*(1.f/128.f) - mu*mu + EPSF);
#pragma unroll
    for (int r = 0; r < 16; ++r) {
      int o = 32*rt + (r&3) + 8*(r>>2) + 4*hi;
      out[((size_t)b*128 + o)*QQ + q0 + lo] = (z2v[r]-mu)*rs*post_g[o] + post_b[o];
    }
  }
}

extern "C" void kernel_launch(void* const* d_in, const int* in_sizes, int n_in,
                              void* d_out, int out_size, void* d_ws, size_t ws_size,
                              hipStream_t stream) {
  const float* x           = (const float*)d_in[0];
  const float* feature     = (const float*)d_in[1];
  const float* I_inv       = (const float*)d_in[2];
  const float* E_inv       = (const float*)d_in[3];
  const float* bev_grid    = (const float*)d_in[4];
  const float* image_plane = (const float*)d_in[5];
  const float* fl_bn_g = (const float*)d_in[6];
  const float* fl_bn_b = (const float*)d_in[7];
  const float* fl_bn_m = (const float*)d_in[8];
  const float* fl_bn_v = (const float*)d_in[9];
  const float* fl_w    = (const float*)d_in[10];
  const float* fp_bn_g = (const float*)d_in[11];
  const float* fp_bn_b = (const float*)d_in[12];
  const float* fp_bn_m = (const float*)d_in[13];
  const float* fp_bn_v = (const float*)d_in[14];
  const float* fp_w    = (const float*)d_in[15];
  const float* bev_w   = (const float*)d_in[16];
  const float* bev_b   = (const float*)d_in[17];
  const float* img_w   = (const float*)d_in[18];
  const float* cam_w   = (const float*)d_in[19];
  const float* q_ln_g  = (const float*)d_in[20];
  const float* q_ln_b  = (const float*)d_in[21];
  const float* q_w     = (const float*)d_in[22];
  const float* q_b     = (const float*)d_in[23];
  const float* k_ln_g  = (const float*)d_in[24];
  const float* k_ln_b  = (const float*)d_in[25];
  const float* k_w     = (const float*)d_in[26];
  const float* k_b     = (const float*)d_in[27];
  const float* v_ln_g  = (const float*)d_in[28];
  const float* v_ln_b  = (const float*)d_in[29];
  const float* v_w     = (const float*)d_in[30];
  const float* v_b     = (const float*)d_in[31];
  const float* proj_w  = (const float*)d_in[32];
  const float* proj_b  = (const float*)d_in[33];
  const float* pre_g   = (const float*)d_in[34];
  const float* pre_b   = (const float*)d_in[35];
  const float* mlp_w1  = (const float*)d_in[36];
  const float* mlp_b1  = (const float*)d_in[37];
  const float* mlp_w2  = (const float*)d_in[38];
  const float* mlp_b2  = (const float*)d_in[39];
  const float* post_g  = (const float*)d_in[40];
  const float* post_b  = (const float*)d_in[41];

  // ws layout: f32 first, then bf16 (all 16B aligned)
  float* ws = (float*)d_ws;
  float* c_embed = ws;                                         // 1536 f32
  float* lsum = ws + 1536;                                     // BB*4*NPART*QQ f32
  unsigned short* pacb = (unsigned short*)(lsum + (size_t)BB*4*NPART*QQ);
  unsigned short* qhb = pacb + (size_t)BB*4*NPART*QQ*32;       // bf16
  unsigned short* khb = qhb + (size_t)BB*NN*QQ*128;
  unsigned short* vtb = khb + (size_t)BB*NN*KPIX*128;
  unsigned short* wpk = vtb + (size_t)BB*NN*KPIX*128;          // WPK_ELEMS bf16
  float* out = (float*)d_out;

  hipLaunchKernelGGL(pre_kernel, dim3(1280 + BB*NN), dim3(128), 0, stream,
                     fp_w, fl_w, k_w, v_w, q_w, proj_w, mlp_w1, mlp_w2,
                     cam_w, E_inv, wpk, c_embed);
  hipLaunchKernelGGL(proj_kernel, dim3(KVGRID + BB*NN*32), dim3(256), 0, stream,
                     feature, I_inv, E_inv, image_plane, c_embed, img_w,
                     fp_bn_g, fp_bn_b, fp_bn_m, fp_bn_v,
                     fl_bn_g, fl_bn_b, fl_bn_m, fl_bn_v,
                     k_ln_g, k_ln_b, k_b,
                     v_ln_g, v_ln_b, v_b,
                     x, bev_grid, bev_w, bev_b,
                     q_ln_g, q_ln_b, q_b,
                     wpk, khb, vtb, qhb);
  hipLaunchKernelGGL(attn_kernel, dim3(BB*16*NN*SPLIT), dim3(256), 0, stream,
                     qhb, khb, vtb, lsum, pacb);
  hipLaunchKernelGGL(epi_kernel, dim3(BB*32), dim3(512), 0, stream,
                     lsum, pacb, x, wpk, proj_b, pre_g, pre_b,
                     mlp_b1, mlp_b2, post_g, post_b, out);
}